// Round 6
// baseline (3978.641 us; speedup 1.0000x reference)
//
#include <hip/hip_runtime.h>
#include <stdint.h>

#define T_LEN 2048
#define L     1024
#define TPBW  1024          // wide block: 16 waves, 64 columns (4 per wave)
#define NCB   16            // chain blocks per direction
#define COLS  64            // columns (rows) per block
#define GOLDW 32            // gold block id
#define TMID  1023          // forward computes f_{1023}; backward computes b_{1023}
#define BSTEPS 1024         // backward step count (s=1..1024, emission row t=2048-s)
#define SPIN_MAX (1 << 14)  // bounded: wedge exits, normal use 1-3 iters

// legacy fallback geometry
#define NFB   64
#define CPB   16
#define TPB   256

#define SCOPE_AGENT __HIP_MEMORY_SCOPE_AGENT
#define SCOPE_WG    __HIP_MEMORY_SCOPE_WORKGROUP
#define LDA(p) __hip_atomic_load((p), __ATOMIC_RELAXED, SCOPE_AGENT)
#define STA(p, v) __hip_atomic_store((p), (v), __ATOMIC_RELAXED, SCOPE_AGENT)

__device__ __forceinline__ uint64_t pack_su(int tag, float v) {
    return ((uint64_t)(uint32_t)tag << 32) | (uint64_t)__float_as_uint(v);
}

// 2-deep pipelined poll of ONE slot: keep two loads in flight so discovery
// granularity ~ half a UC load latency. Thread-local address (no hot line).
static __device__ __forceinline__ uint64_t poll_slot(const uint64_t* p, int expect) {
    uint64_t va = LDA(p);
    int n = 0;
    for (;;) {
        uint64_t vb = LDA(p);                       // issue next before checking va
        if ((int)(va >> 32) >= expect) return va;
        if (++n >= SPIN_MAX) return vb;
        va = vb;
    }
}

// =====================================================================
// v6: wide-block MITM, v4 poll structure (own slot only), both block
// barriers removed from the step path:
//   - shift = block's own column value from step t-2 (LDS, lgkm-fenced
//     before the t-2 global publish; causally visible via the poll chain)
//     -> replaces barrier #2. NO extra global poll (v5's mistake).
//   - per-wave chunk flags (release/acquire LDS) replace barrier #1.
//   - 2-deep pipelined own-slot poll.
// ws layout (u64): fb0[L] fb1[L] bb0[L] bb1[L] gold
// Requires ws >= (4*L + 1) * 8 = 32776 bytes.
// =====================================================================
__global__ __launch_bounds__(TPBW, 1)
void crf_v6(const float* __restrict__ feats,
            const float* __restrict__ transfer,
            const int* __restrict__ target,
            float* __restrict__ out,
            uint64_t* __restrict__ ws64)
{
    __shared__ __align__(16) float qbuf[2][L];      // 8 KB, double-buffered
    __shared__ int   ready[2][16];                  // per-parity per-wave chunk tags
    __shared__ float shp[2];                        // per-parity stale shift
    __shared__ float red[32];                       // combine/gold scratch

    uint64_t* fb0 = ws64;
    uint64_t* fb1 = ws64 + L;
    uint64_t* bb0 = ws64 + 2 * L;
    uint64_t* bb1 = ws64 + 3 * L;
    uint64_t* goldslot = ws64 + 4 * L;

    const int bid  = blockIdx.x;
    const int tid  = threadIdx.x;                    // 0..1023
    const int lane = tid & 63;
    const int wv   = tid >> 6;                       // wave 0..15
    const int cl   = 2 * (lane & 1) + ((lane >> 1) & 1);   // bijective on lanes 0..3

    // ---------------- gold block ----------------
    if (bid == GOLDW) {
        float s = 0.f;
        for (int t = tid; t < T_LEN; t += TPBW)
            s += feats[t * L + target[t]];
        for (int t = tid; t < T_LEN - 1; t += TPBW)
            s += transfer[target[t] * L + target[t + 1]];
        #pragma unroll
        for (int m = 32; m; m >>= 1) s += __shfl_xor(s, m, 64);
        if (lane == 0) red[wv] = s;
        __syncthreads();
        if (tid == 0) {
            float g = 0.f;
            #pragma unroll
            for (int i = 0; i < 16; ++i) g += red[i];
            STA(goldslot, pack_su(1, g));
        }
        return;
    }

    // chain blocks: init flags once
    if (tid < 32) ready[tid >> 4][tid & 15] = 0;
    __syncthreads();

    if (bid < NCB) {
        // ================= FORWARD chain (16 blocks, 1023 steps) =================
        const int role    = bid;
        const int colbase = role * COLS;
        const int gcb     = colbase + 4 * wv;        // wave's first global column

        float E[16][4];                              // E[k][c]=exp(transfer[lane+64k][gcb+c])
        #pragma unroll
        for (int k = 0; k < 16; ++k) {
            const float4 r = *(const float4*)(transfer + (size_t)(lane + 64 * k) * L + gcb);
            E[k][0] = __expf(r.x); E[k][1] = __expf(r.y);
            E[k][2] = __expf(r.z); E[k][3] = __expf(r.w);
        }
        const float shift0 = feats[colbase];         // shift for t=1,2 (block-uniform)

        for (int t = 1; t <= TMID; ++t) {
            const int par = t & 1;
            const uint64_t* rbuf = par ? fb0 : fb1;  // written at t-1
            uint64_t* wbuf = par ? fb1 : fb0;
            const int expect = t - 1;

            const float fe = feats[(size_t)t * L + gcb + cl];   // overlaps poll

            float val, sloc;
            if (t == 1) {
                val  = feats[tid];                   // f_0 = feats[0][tid], direct
                sloc = shift0;
            } else {
                sloc = (t == 2) ? shift0
                                : __hip_atomic_load(&shp[par], __ATOMIC_RELAXED, SCOPE_WG);
                const uint64_t v = poll_slot(rbuf + tid, expect);
                val = __uint_as_float((uint32_t)v);
            }

            float* qb = qbuf[par];
            qb[tid] = __expf(val - sloc);
            if (lane == 0)   // release orders the wave's qb ds_write before the flag
                __hip_atomic_store(&ready[par][wv], t, __ATOMIC_RELEASE, SCOPE_WG);

            float a0 = 0.f, a1 = 0.f, a2 = 0.f, a3 = 0.f;
            #pragma unroll
            for (int k = 0; k < 16; ++k) {
                if (k != wv) {
                    int n2 = 0;
                    while (__hip_atomic_load(&ready[par][k], __ATOMIC_ACQUIRE, SCOPE_WG) < t
                           && ++n2 < SPIN_MAX) {}
                }
                const float q = qb[lane + 64 * k];   // conflict-free ds_read_b32
                a0 += q * E[k][0]; a1 += q * E[k][1];
                a2 += q * E[k][2]; a3 += q * E[k][3];
            }

            {   // split-reduction: 4 accs -> 1 per lane (col = cl)
                const bool h1 = lane & 1;
                float s0 = h1 ? a0 : a2;  float r0 = __shfl_xor(s0, 1, 64);
                float s1 = h1 ? a1 : a3;  float r1 = __shfl_xor(s1, 1, 64);
                a0 = (h1 ? a2 : a0) + r0;
                a1 = (h1 ? a3 : a1) + r1;
                const bool h2 = lane & 2;
                float s2 = h2 ? a0 : a1;  float r2 = __shfl_xor(s2, 2, 64);
                a0 = (h2 ? a1 : a0) + r2;
            }
            float s = a0;
            s += __shfl_xor(s, 4, 64);
            s += __shfl_xor(s, 8, 64);
            s += __shfl_xor(s, 16, 64);
            s += __shfl_xor(s, 32, 64);

            const float nv = sloc + __logf(s) + fe;

            if (wv == 0) {
                // lane 0 holds column colbase (cl==0): stash shift for t+2,
                // fence LDS completion BEFORE the global publish (causality).
                if (lane == 0)
                    __hip_atomic_store(&shp[par], nv, __ATOMIC_RELAXED, SCOPE_WG);
                asm volatile("s_waitcnt lgkmcnt(0)" ::: "memory");
                __builtin_amdgcn_sched_barrier(0);
            }
            if (lane < 4)
                STA(&wbuf[gcb + cl], pack_su(t, nv));
        }

        // ---------- role 0: logZ = lse(f_{1023} + b_{1023}) - gold ----------
        if (role == 0) {
            const uint64_t* fp = fb1 + tid;          // t=1023 odd -> fb1
            const uint64_t* bp = bb0 + tid;          // s=1024 even -> bb0
            uint64_t fv_, bv_;
            int n = 0;
            for (;;) {
                fv_ = LDA(fp); bv_ = LDA(bp);
                bool ok = ((int)(fv_ >> 32) >= TMID) & ((int)(bv_ >> 32) >= BSTEPS);
                if (ok || ++n >= SPIN_MAX) break;
            }
            const float sv = __uint_as_float((uint32_t)fv_) + __uint_as_float((uint32_t)bv_);
            float mx = sv;
            #pragma unroll
            for (int m = 32; m; m >>= 1) mx = fmaxf(mx, __shfl_xor(mx, m, 64));
            if (lane == 0) red[wv] = mx;
            __syncthreads();
            float M = red[0];
            #pragma unroll
            for (int i = 1; i < 16; ++i) M = fmaxf(M, red[i]);
            float sm = __expf(sv - M);
            #pragma unroll
            for (int m = 32; m; m >>= 1) sm += __shfl_xor(sm, m, 64);
            if (lane == 0) red[16 + wv] = sm;
            __syncthreads();
            if (tid == 0) {
                float S = 0.f;
                #pragma unroll
                for (int i = 0; i < 16; ++i) S += red[16 + i];
                const float lse = M + __logf(S);
                uint64_t g = LDA(goldslot);
                int n2 = 0;
                while ((int)(g >> 32) < 1 && ++n2 < SPIN_MAX) g = LDA(goldslot);
                out[0] = lse - __uint_as_float((uint32_t)g);
            }
        }
        return;
    }

    if (bid < 2 * NCB) {
        // ================= BACKWARD chain (16 blocks, 1024 steps) =================
        const int role    = bid - NCB;
        const int rowbase = role * COLS + 4 * wv;    // wave's first global row

        // E[k][r] = exp(transfer[(rowbase+r)*L + lane+64k]) — coalesced staging
        float E[16][4];
        #pragma unroll
        for (int r = 0; r < 4; ++r) {
            const float* rowp = transfer + (size_t)(rowbase + r) * L + lane;
            #pragma unroll
            for (int k = 0; k < 16; ++k)
                E[k][r] = __expf(rowp[64 * k]);
        }

        for (int s = 1; s <= BSTEPS; ++s) {
            const int par = s & 1;
            const uint64_t* rbuf = par ? bb0 : bb1;
            uint64_t* wbuf = par ? bb1 : bb0;
            const int expect = s - 1;
            const int t = T_LEN - s;                 // emission row for this step

            const float fvv = feats[(size_t)t * L + tid];   // overlaps poll

            float bval, sb;
            if (s == 1) {
                bval = 0.f; sb = 0.f;                // b_{2047} = 0
            } else {
                sb = (s == 2) ? 0.f
                              : __hip_atomic_load(&shp[par], __ATOMIC_RELAXED, SCOPE_WG);
                const uint64_t v = poll_slot(rbuf + tid, expect);
                bval = __uint_as_float((uint32_t)v);
            }

            // w_j = exp(feats[t][j] + b[j] - sb) -> LDS broadcast
            float* qb = qbuf[par];
            qb[tid] = __expf(fvv + bval - sb);
            if (lane == 0)
                __hip_atomic_store(&ready[par][wv], s, __ATOMIC_RELEASE, SCOPE_WG);

            // matvec: acc[r] += w[lane+64k] * E[k][r], chunks consumed as ready
            float a0 = 0.f, a1 = 0.f, a2 = 0.f, a3 = 0.f;
            #pragma unroll
            for (int k = 0; k < 16; ++k) {
                if (k != wv) {
                    int n2 = 0;
                    while (__hip_atomic_load(&ready[par][k], __ATOMIC_ACQUIRE, SCOPE_WG) < s
                           && ++n2 < SPIN_MAX) {}
                }
                const float w = qb[lane + 64 * k];
                a0 += w * E[k][0]; a1 += w * E[k][1];
                a2 += w * E[k][2]; a3 += w * E[k][3];
            }

            {   // split-reduction: 4 accs -> 1 per lane (row = cl)
                const bool h1 = lane & 1;
                float s0 = h1 ? a0 : a2;  float r0 = __shfl_xor(s0, 1, 64);
                float s1 = h1 ? a1 : a3;  float r1 = __shfl_xor(s1, 1, 64);
                a0 = (h1 ? a2 : a0) + r0;
                a1 = (h1 ? a3 : a1) + r1;
                const bool h2 = lane & 2;
                float s2 = h2 ? a0 : a1;  float r2 = __shfl_xor(s2, 2, 64);
                a0 = (h2 ? a1 : a0) + r2;
            }
            float sum = a0;
            sum += __shfl_xor(sum, 4, 64);
            sum += __shfl_xor(sum, 8, 64);
            sum += __shfl_xor(sum, 16, 64);
            sum += __shfl_xor(sum, 32, 64);

            const float nb = sb + __logf(sum);       // emission already inside w

            if (wv == 0) {
                if (lane == 0)
                    __hip_atomic_store(&shp[par], nb, __ATOMIC_RELAXED, SCOPE_WG);
                asm volatile("s_waitcnt lgkmcnt(0)" ::: "memory");
                __builtin_amdgcn_sched_barrier(0);
            }
            if (lane < 4)
                STA(&wbuf[rowbase + cl], pack_su(s, nb));
        }
        return;
    }
}

// =====================================================================
// Fallback: proven single-forward-chain kernel (4.16 ms).
// Requires only (2*L + 1) * 8 = 16392 bytes of ws.
// =====================================================================
__global__ __launch_bounds__(TPB, 1)
void crf_single(const float* __restrict__ feats,
                const float* __restrict__ transfer,
                const int* __restrict__ target,
                float* __restrict__ out,
                uint64_t* __restrict__ ws64)
{
    __shared__ __align__(16) float qbuf[2][L];
    __shared__ float red[8];

    uint64_t* buf0 = ws64;
    uint64_t* buf1 = ws64 + L;
    uint64_t* goldslot = ws64 + 2 * L;

    const int b   = blockIdx.x;
    const int tid = threadIdx.x;
    const int lane = tid & 63;
    const int wv   = tid >> 6;
    const int cl   = 2 * (lane & 1) + ((lane >> 1) & 1);

    if (b == NFB) {
        float s = 0.f;
        for (int t = tid; t < T_LEN; t += TPB)
            s += feats[t * L + target[t]];
        for (int t = tid; t < T_LEN - 1; t += TPB)
            s += transfer[target[t] * L + target[t + 1]];
        #pragma unroll
        for (int m = 32; m; m >>= 1) s += __shfl_xor(s, m, 64);
        if (lane == 0) red[wv] = s;
        __syncthreads();
        if (tid == 0) {
            float g = red[0] + red[1] + red[2] + red[3];
            STA(goldslot, pack_su(1, g));
        }
        return;
    }

    const int gcb    = b * CPB + 4 * wv;
    const int shslot = b * CPB;

    float E[16][4];
    #pragma unroll
    for (int k = 0; k < 16; ++k) {
        const float4 r = *(const float4*)(transfer + (size_t)(lane + 64 * k) * L + gcb);
        E[k][0] = __expf(r.x); E[k][1] = __expf(r.y);
        E[k][2] = __expf(r.z); E[k][3] = __expf(r.w);
    }

    if (tid < CPB) {
        int j = b * CPB + tid;
        STA(&buf0[j], pack_su(0, feats[j]));
    }

    for (int t = 1; t < T_LEN; ++t) {
        uint64_t* rbuf = (t & 1) ? buf0 : buf1;
        uint64_t* wbuf = (t & 1) ? buf1 : buf0;
        const int expect = t - 1;
        const float fe = feats[(size_t)t * L + gcb + cl];

        const uint64_t* rp = rbuf + 4 * tid;
        uint64_t v0, v1, v2, v3, vs;
        int n = 0;
        for (;;) {
            v0 = LDA(rp + 0); v1 = LDA(rp + 1);
            v2 = LDA(rp + 2); v3 = LDA(rp + 3);
            vs = LDA(rbuf + shslot);
            bool ready = ((int)(v0 >> 32) >= expect) & ((int)(v1 >> 32) >= expect) &
                         ((int)(v2 >> 32) >= expect) & ((int)(v3 >> 32) >= expect) &
                         ((int)(vs >> 32) >= expect);
            if (ready || ++n >= SPIN_MAX) break;
        }
        const float sloc = __uint_as_float((uint32_t)vs);

        float* qb = qbuf[t & 1];
        float4 qv;
        qv.x = __expf(__uint_as_float((uint32_t)v0) - sloc);
        qv.y = __expf(__uint_as_float((uint32_t)v1) - sloc);
        qv.z = __expf(__uint_as_float((uint32_t)v2) - sloc);
        qv.w = __expf(__uint_as_float((uint32_t)v3) - sloc);
        ((float4*)qb)[tid] = qv;
        __syncthreads();

        float a0 = 0.f, a1 = 0.f, a2 = 0.f, a3 = 0.f;
        #pragma unroll
        for (int k = 0; k < 16; ++k) {
            const float q = qb[lane + 64 * k];
            a0 += q * E[k][0]; a1 += q * E[k][1];
            a2 += q * E[k][2]; a3 += q * E[k][3];
        }
        {
            const bool h1 = lane & 1;
            float s0 = h1 ? a0 : a2;  float r0 = __shfl_xor(s0, 1, 64);
            float s1 = h1 ? a1 : a3;  float r1 = __shfl_xor(s1, 1, 64);
            a0 = (h1 ? a2 : a0) + r0;
            a1 = (h1 ? a3 : a1) + r1;
            const bool h2 = lane & 2;
            float s2 = h2 ? a0 : a1;  float r2 = __shfl_xor(s2, 2, 64);
            a0 = (h2 ? a1 : a0) + r2;
        }
        float s = a0;
        s += __shfl_xor(s, 4, 64);
        s += __shfl_xor(s, 8, 64);
        s += __shfl_xor(s, 16, 64);
        s += __shfl_xor(s, 32, 64);

        const float nv = sloc + __logf(s) + fe;
        if (lane < 4)
            STA(&wbuf[gcb + cl], pack_su(t, nv));
    }

    if (b == 0) {
        const uint64_t* fp = buf1 + 4 * tid;
        uint64_t v0, v1, v2, v3;
        int n = 0;
        for (;;) {
            v0 = LDA(fp + 0); v1 = LDA(fp + 1);
            v2 = LDA(fp + 2); v3 = LDA(fp + 3);
            bool ready = ((int)(v0 >> 32) >= T_LEN - 1) & ((int)(v1 >> 32) >= T_LEN - 1) &
                         ((int)(v2 >> 32) >= T_LEN - 1) & ((int)(v3 >> 32) >= T_LEN - 1);
            if (ready || ++n >= SPIN_MAX) break;
        }
        float sv[4] = { __uint_as_float((uint32_t)v0), __uint_as_float((uint32_t)v1),
                        __uint_as_float((uint32_t)v2), __uint_as_float((uint32_t)v3) };
        float mx = fmaxf(fmaxf(sv[0], sv[1]), fmaxf(sv[2], sv[3]));
        #pragma unroll
        for (int m = 32; m; m >>= 1) mx = fmaxf(mx, __shfl_xor(mx, m, 64));
        if (lane == 0) red[wv] = mx;
        __syncthreads();
        const float M = fmaxf(fmaxf(red[0], red[1]), fmaxf(red[2], red[3]));
        float sm = 0.f;
        #pragma unroll
        for (int k = 0; k < 4; ++k) sm += __expf(sv[k] - M);
        #pragma unroll
        for (int m = 32; m; m >>= 1) sm += __shfl_xor(sm, m, 64);
        if (lane == 0) red[4 + wv] = sm;
        __syncthreads();
        if (tid == 0) {
            const float S = red[4] + red[5] + red[6] + red[7];
            const float lse = M + __logf(S);
            uint64_t g = LDA(goldslot);
            int n2 = 0;
            while ((int)(g >> 32) < 1 && ++n2 < SPIN_MAX) g = LDA(goldslot);
            out[0] = lse - __uint_as_float((uint32_t)g);
        }
    }
}

extern "C" void kernel_launch(void* const* d_in, const int* in_sizes, int n_in,
                              void* d_out, int out_size, void* d_ws, size_t ws_size,
                              hipStream_t stream) {
    const float* feats    = (const float*)d_in[0];
    const float* transfer = (const float*)d_in[1];
    const int*   target   = (const int*)d_in[2];
    float* out = (float*)d_out;
    uint64_t* ws64 = (uint64_t*)d_ws;

    if (ws_size >= (4 * L + 1) * sizeof(uint64_t)) {
        // wide-block MITM, barrier-free step path (stale shift + chunk flags)
        hipLaunchKernelGGL(crf_v6, dim3(GOLDW + 1), dim3(TPBW), 0, stream,
                           feats, transfer, target, out, ws64);
    } else {
        // proven single-chain fallback (R4): needs only 16392 B of ws
        hipLaunchKernelGGL(crf_single, dim3(NFB + 1), dim3(TPB), 0, stream,
                           feats, transfer, target, out, ws64);
    }
}

// Round 8
// 3086.198 us; speedup vs baseline: 1.2892x; 1.2892x over previous
//
#include <hip/hip_runtime.h>
#include <stdint.h>

#define T_LEN 2048
#define L     1024
#define TPBW  1024          // wide block: 16 waves, 64 columns (4 per wave)
#define NCB   16            // chain blocks per direction
#define COLS  64            // columns (rows) per block
#define GOLDW 32            // gold block id
#define TMID  1023          // forward computes f_{1023}; backward computes b_{1023}
#define BSTEPS 1024         // backward step count (s=1..1024, emission row t=2048-s)
#define SPIN_MAX (1 << 14)  // bounded: wedge exits, normal use 1-3 iters

// legacy fallback geometry
#define NFB   64
#define CPB   16
#define TPB   256

#define SCOPE_AGENT __HIP_MEMORY_SCOPE_AGENT
#define LDA(p) __hip_atomic_load((p), __ATOMIC_RELAXED, SCOPE_AGENT)
#define STA(p, v) __hip_atomic_store((p), (v), __ATOMIC_RELAXED, SCOPE_AGENT)

__device__ __forceinline__ uint64_t pack_su(int tag, float v) {
    return ((uint64_t)(uint32_t)tag << 32) | (uint64_t)__float_as_uint(v);
}

// 2-deep pipelined poll of ONE slot: keep two loads in flight so discovery
// granularity ~ half a UC load latency. Thread-local address (no hot lines).
static __device__ __forceinline__ uint64_t poll_slot(const uint64_t* p, int expect) {
    uint64_t va = LDA(p);
    int n = 0;
    for (;;) {
        uint64_t vb = LDA(p);                        // next load in flight before check
        if ((int)(va >> 32) >= expect) return va;
        if (++n >= SPIN_MAX) return vb;
        va = vb;
    }
}

// =====================================================================
// v7 = v4 skeleton (hardware barrier for intra-block sync, own-slot
// agent polls — both proven at 1679 us) + two spin-free cuts:
//   - ONE __syncthreads per step (was 2): shift publication moved to
//     parity-double-buffered shp[2] with a t-2-stale value; the write
//     (end of step t) and read (start of step t+2) are ordered by the
//     step-t+1 barrier. Published values are shift-independent; 2-step
//     drift << fp32 exp range.
//   - 2-deep pipelined own-slot poll (halved discovery granularity).
//   NO spin-flag sync (v5/v6 lesson: spinning waves burn issue slots
//   and starve producers; s_barrier parks waves in hardware).
// ws layout (u64): fb0[L] fb1[L] bb0[L] bb1[L] gold
// Requires ws >= (4*L + 1) * 8 = 32776 bytes.
// =====================================================================
__global__ __launch_bounds__(TPBW, 1)
void crf_v7(const float* __restrict__ feats,
            const float* __restrict__ transfer,
            const int* __restrict__ target,
            float* __restrict__ out,
            uint64_t* __restrict__ ws64)
{
    __shared__ __align__(16) float qbuf[2][L];      // 8 KB, double-buffered
    __shared__ float shp[2];                        // per-parity stale shift
    __shared__ float red[32];                       // combine/gold scratch

    uint64_t* fb0 = ws64;
    uint64_t* fb1 = ws64 + L;
    uint64_t* bb0 = ws64 + 2 * L;
    uint64_t* bb1 = ws64 + 3 * L;
    uint64_t* goldslot = ws64 + 4 * L;

    const int bid  = blockIdx.x;
    const int tid  = threadIdx.x;                    // 0..1023
    const int lane = tid & 63;
    const int wv   = tid >> 6;                       // wave 0..15
    const int cl   = 2 * (lane & 1) + ((lane >> 1) & 1);   // bijective on lanes 0..3

    // ---------------- gold block ----------------
    if (bid == GOLDW) {
        float s = 0.f;
        for (int t = tid; t < T_LEN; t += TPBW)
            s += feats[t * L + target[t]];
        for (int t = tid; t < T_LEN - 1; t += TPBW)
            s += transfer[target[t] * L + target[t + 1]];
        #pragma unroll
        for (int m = 32; m; m >>= 1) s += __shfl_xor(s, m, 64);
        if (lane == 0) red[wv] = s;
        __syncthreads();
        if (tid == 0) {
            float g = 0.f;
            #pragma unroll
            for (int i = 0; i < 16; ++i) g += red[i];
            STA(goldslot, pack_su(1, g));
        }
        return;
    }

    if (bid < NCB) {
        // ================= FORWARD chain (16 blocks, 1023 steps) =================
        const int role    = bid;
        const int colbase = role * COLS;
        const int gcb     = colbase + 4 * wv;        // wave's first global column

        float E[16][4];                              // E[k][c]=exp(transfer[lane+64k][gcb+c])
        #pragma unroll
        for (int k = 0; k < 16; ++k) {
            const float4 r = *(const float4*)(transfer + (size_t)(lane + 64 * k) * L + gcb);
            E[k][0] = __expf(r.x); E[k][1] = __expf(r.y);
            E[k][2] = __expf(r.z); E[k][3] = __expf(r.w);
        }
        const float shift0 = feats[colbase];         // block-uniform shift for t=1,2

        for (int t = 1; t <= TMID; ++t) {
            const int par = t & 1;
            const uint64_t* rbuf = par ? fb0 : fb1;  // written at t-1
            uint64_t* wbuf = par ? fb1 : fb0;
            const int expect = t - 1;

            const float fe = feats[(size_t)t * L + gcb + cl];   // overlaps poll

            float val, sloc;
            if (t == 1) {
                val  = feats[tid];                   // f_0 = feats[0][tid], direct
                sloc = shift0;
            } else {
                // stale shift: own column value from step t-2 (ordered by the
                // step-(t-1) barrier); t==2 falls back to the t=0 constant.
                sloc = (t == 2) ? shift0 : shp[par];
                const uint64_t v = poll_slot(rbuf + tid, expect);
                val = __uint_as_float((uint32_t)v);
            }

            float* qb = qbuf[par];
            qb[tid] = __expf(val - sloc);
            __syncthreads();                         // the ONE barrier per step

            float a0 = 0.f, a1 = 0.f, a2 = 0.f, a3 = 0.f;
            #pragma unroll
            for (int k = 0; k < 16; ++k) {
                const float q = qb[lane + 64 * k];   // conflict-free ds_read_b32
                a0 += q * E[k][0]; a1 += q * E[k][1];
                a2 += q * E[k][2]; a3 += q * E[k][3];
            }

            {   // split-reduction: 4 accs -> 1 per lane (col = cl)
                const bool h1 = lane & 1;
                float s0 = h1 ? a0 : a2;  float r0 = __shfl_xor(s0, 1, 64);
                float s1 = h1 ? a1 : a3;  float r1 = __shfl_xor(s1, 1, 64);
                a0 = (h1 ? a2 : a0) + r0;
                a1 = (h1 ? a3 : a1) + r1;
                const bool h2 = lane & 2;
                float s2 = h2 ? a0 : a1;  float r2 = __shfl_xor(s2, 2, 64);
                a0 = (h2 ? a1 : a0) + r2;
            }
            float s = a0;
            s += __shfl_xor(s, 4, 64);
            s += __shfl_xor(s, 8, 64);
            s += __shfl_xor(s, 16, 64);
            s += __shfl_xor(s, 32, 64);

            const float nv = sloc + __logf(s) + fe;
            if (lane < 4)
                STA(&wbuf[gcb + cl], pack_su(t, nv));
            if (tid == 0) shp[par] = nv;             // shift for step t+2 (col colbase)
            // no second barrier: ordered by next step's __syncthreads
        }

        // ---------- role 0: logZ = lse(f_{1023} + b_{1023}) - gold ----------
        if (role == 0) {
            const uint64_t* fp = fb1 + tid;          // t=1023 odd -> fb1
            const uint64_t* bp = bb0 + tid;          // s=1024 even -> bb0
            uint64_t fv_, bv_;
            int n = 0;
            for (;;) {
                fv_ = LDA(fp); bv_ = LDA(bp);
                bool ok = ((int)(fv_ >> 32) >= TMID) & ((int)(bv_ >> 32) >= BSTEPS);
                if (ok || ++n >= SPIN_MAX) break;
            }
            const float sv = __uint_as_float((uint32_t)fv_) + __uint_as_float((uint32_t)bv_);
            float mx = sv;
            #pragma unroll
            for (int m = 32; m; m >>= 1) mx = fmaxf(mx, __shfl_xor(mx, m, 64));
            if (lane == 0) red[wv] = mx;
            __syncthreads();
            float M = red[0];
            #pragma unroll
            for (int i = 1; i < 16; ++i) M = fmaxf(M, red[i]);
            float sm = __expf(sv - M);
            #pragma unroll
            for (int m = 32; m; m >>= 1) sm += __shfl_xor(sm, m, 64);
            if (lane == 0) red[16 + wv] = sm;
            __syncthreads();
            if (tid == 0) {
                float S = 0.f;
                #pragma unroll
                for (int i = 0; i < 16; ++i) S += red[16 + i];
                const float lse = M + __logf(S);
                uint64_t g = LDA(goldslot);
                int n2 = 0;
                while ((int)(g >> 32) < 1 && ++n2 < SPIN_MAX) g = LDA(goldslot);
                out[0] = lse - __uint_as_float((uint32_t)g);
            }
        }
        return;
    }

    if (bid < 2 * NCB) {
        // ================= BACKWARD chain (16 blocks, 1024 steps) =================
        const int role    = bid - NCB;
        const int rowbase = role * COLS + 4 * wv;    // wave's first global row

        // E[k][r] = exp(transfer[(rowbase+r)*L + lane+64k]) — coalesced staging
        float E[16][4];
        #pragma unroll
        for (int r = 0; r < 4; ++r) {
            const float* rowp = transfer + (size_t)(rowbase + r) * L + lane;
            #pragma unroll
            for (int k = 0; k < 16; ++k)
                E[k][r] = __expf(rowp[64 * k]);
        }

        for (int s = 1; s <= BSTEPS; ++s) {
            const int par = s & 1;
            const uint64_t* rbuf = par ? bb0 : bb1;
            uint64_t* wbuf = par ? bb1 : bb0;
            const int expect = s - 1;
            const int t = T_LEN - s;                 // emission row for this step

            const float fvv = feats[(size_t)t * L + tid];   // overlaps poll

            float bval, sb;
            if (s == 1) {
                bval = 0.f; sb = 0.f;                // b_{2047} = 0
            } else {
                sb = (s == 2) ? 0.f : shp[par];      // stale shift from step s-2
                const uint64_t v = poll_slot(rbuf + tid, expect);
                bval = __uint_as_float((uint32_t)v);
            }

            // w_j = exp(feats[t][j] + b[j] - sb) -> LDS broadcast
            float* qb = qbuf[par];
            qb[tid] = __expf(fvv + bval - sb);
            __syncthreads();                         // the ONE barrier per step

            // matvec: acc[r] += w[lane+64k] * E[k][r]
            float a0 = 0.f, a1 = 0.f, a2 = 0.f, a3 = 0.f;
            #pragma unroll
            for (int k = 0; k < 16; ++k) {
                const float w = qb[lane + 64 * k];
                a0 += w * E[k][0]; a1 += w * E[k][1];
                a2 += w * E[k][2]; a3 += w * E[k][3];
            }

            {   // split-reduction: 4 accs -> 1 per lane (row = cl)
                const bool h1 = lane & 1;
                float s0 = h1 ? a0 : a2;  float r0 = __shfl_xor(s0, 1, 64);
                float s1 = h1 ? a1 : a3;  float r1 = __shfl_xor(s1, 1, 64);
                a0 = (h1 ? a2 : a0) + r0;
                a1 = (h1 ? a3 : a1) + r1;
                const bool h2 = lane & 2;
                float s2 = h2 ? a0 : a1;  float r2 = __shfl_xor(s2, 2, 64);
                a0 = (h2 ? a1 : a0) + r2;
            }
            float sum = a0;
            sum += __shfl_xor(sum, 4, 64);
            sum += __shfl_xor(sum, 8, 64);
            sum += __shfl_xor(sum, 16, 64);
            sum += __shfl_xor(sum, 32, 64);

            const float nb = sb + __logf(sum);       // emission already inside w
            if (lane < 4)
                STA(&wbuf[rowbase + cl], pack_su(s, nb));
            if (tid == 0) shp[par] = nb;             // shift for step s+2
        }
        return;
    }
}

// =====================================================================
// Fallback: proven single-forward-chain kernel (4.16 ms).
// Requires only (2*L + 1) * 8 = 16392 bytes of ws.
// =====================================================================
__global__ __launch_bounds__(TPB, 1)
void crf_single(const float* __restrict__ feats,
                const float* __restrict__ transfer,
                const int* __restrict__ target,
                float* __restrict__ out,
                uint64_t* __restrict__ ws64)
{
    __shared__ __align__(16) float qbuf[2][L];
    __shared__ float red[8];

    uint64_t* buf0 = ws64;
    uint64_t* buf1 = ws64 + L;
    uint64_t* goldslot = ws64 + 2 * L;

    const int b   = blockIdx.x;
    const int tid = threadIdx.x;
    const int lane = tid & 63;
    const int wv   = tid >> 6;
    const int cl   = 2 * (lane & 1) + ((lane >> 1) & 1);

    if (b == NFB) {
        float s = 0.f;
        for (int t = tid; t < T_LEN; t += TPB)
            s += feats[t * L + target[t]];
        for (int t = tid; t < T_LEN - 1; t += TPB)
            s += transfer[target[t] * L + target[t + 1]];
        #pragma unroll
        for (int m = 32; m; m >>= 1) s += __shfl_xor(s, m, 64);
        if (lane == 0) red[wv] = s;
        __syncthreads();
        if (tid == 0) {
            float g = red[0] + red[1] + red[2] + red[3];
            STA(goldslot, pack_su(1, g));
        }
        return;
    }

    const int gcb    = b * CPB + 4 * wv;
    const int shslot = b * CPB;

    float E[16][4];
    #pragma unroll
    for (int k = 0; k < 16; ++k) {
        const float4 r = *(const float4*)(transfer + (size_t)(lane + 64 * k) * L + gcb);
        E[k][0] = __expf(r.x); E[k][1] = __expf(r.y);
        E[k][2] = __expf(r.z); E[k][3] = __expf(r.w);
    }

    if (tid < CPB) {
        int j = b * CPB + tid;
        STA(&buf0[j], pack_su(0, feats[j]));
    }

    for (int t = 1; t < T_LEN; ++t) {
        uint64_t* rbuf = (t & 1) ? buf0 : buf1;
        uint64_t* wbuf = (t & 1) ? buf1 : buf0;
        const int expect = t - 1;
        const float fe = feats[(size_t)t * L + gcb + cl];

        const uint64_t* rp = rbuf + 4 * tid;
        uint64_t v0, v1, v2, v3, vs;
        int n = 0;
        for (;;) {
            v0 = LDA(rp + 0); v1 = LDA(rp + 1);
            v2 = LDA(rp + 2); v3 = LDA(rp + 3);
            vs = LDA(rbuf + shslot);
            bool ready = ((int)(v0 >> 32) >= expect) & ((int)(v1 >> 32) >= expect) &
                         ((int)(v2 >> 32) >= expect) & ((int)(v3 >> 32) >= expect) &
                         ((int)(vs >> 32) >= expect);
            if (ready || ++n >= SPIN_MAX) break;
        }
        const float sloc = __uint_as_float((uint32_t)vs);

        float* qb = qbuf[t & 1];
        float4 qv;
        qv.x = __expf(__uint_as_float((uint32_t)v0) - sloc);
        qv.y = __expf(__uint_as_float((uint32_t)v1) - sloc);
        qv.z = __expf(__uint_as_float((uint32_t)v2) - sloc);
        qv.w = __expf(__uint_as_float((uint32_t)v3) - sloc);
        ((float4*)qb)[tid] = qv;
        __syncthreads();

        float a0 = 0.f, a1 = 0.f, a2 = 0.f, a3 = 0.f;
        #pragma unroll
        for (int k = 0; k < 16; ++k) {
            const float q = qb[lane + 64 * k];
            a0 += q * E[k][0]; a1 += q * E[k][1];
            a2 += q * E[k][2]; a3 += q * E[k][3];
        }
        {
            const bool h1 = lane & 1;
            float s0 = h1 ? a0 : a2;  float r0 = __shfl_xor(s0, 1, 64);
            float s1 = h1 ? a1 : a3;  float r1 = __shfl_xor(s1, 1, 64);
            a0 = (h1 ? a2 : a0) + r0;
            a1 = (h1 ? a3 : a1) + r1;
            const bool h2 = lane & 2;
            float s2 = h2 ? a0 : a1;  float r2 = __shfl_xor(s2, 2, 64);
            a0 = (h2 ? a1 : a0) + r2;
        }
        float s = a0;
        s += __shfl_xor(s, 4, 64);
        s += __shfl_xor(s, 8, 64);
        s += __shfl_xor(s, 16, 64);
        s += __shfl_xor(s, 32, 64);

        const float nv = sloc + __logf(s) + fe;
        if (lane < 4)
            STA(&wbuf[gcb + cl], pack_su(t, nv));
    }

    if (b == 0) {
        const uint64_t* fp = buf1 + 4 * tid;
        uint64_t v0, v1, v2, v3;
        int n = 0;
        for (;;) {
            v0 = LDA(fp + 0); v1 = LDA(fp + 1);
            v2 = LDA(fp + 2); v3 = LDA(fp + 3);
            bool ready = ((int)(v0 >> 32) >= T_LEN - 1) & ((int)(v1 >> 32) >= T_LEN - 1) &
                         ((int)(v2 >> 32) >= T_LEN - 1) & ((int)(v3 >> 32) >= T_LEN - 1);
            if (ready || ++n >= SPIN_MAX) break;
        }
        float sv[4] = { __uint_as_float((uint32_t)v0), __uint_as_float((uint32_t)v1),
                        __uint_as_float((uint32_t)v2), __uint_as_float((uint32_t)v3) };
        float mx = fmaxf(fmaxf(sv[0], sv[1]), fmaxf(sv[2], sv[3]));
        #pragma unroll
        for (int m = 32; m; m >>= 1) mx = fmaxf(mx, __shfl_xor(mx, m, 64));
        if (lane == 0) red[wv] = mx;
        __syncthreads();
        const float M = fmaxf(fmaxf(red[0], red[1]), fmaxf(red[2], red[3]));
        float sm = 0.f;
        #pragma unroll
        for (int k = 0; k < 4; ++k) sm += __expf(sv[k] - M);
        #pragma unroll
        for (int m = 32; m; m >>= 1) sm += __shfl_xor(sm, m, 64);
        if (lane == 0) red[4 + wv] = sm;
        __syncthreads();
        if (tid == 0) {
            const float S = red[4] + red[5] + red[6] + red[7];
            const float lse = M + __logf(S);
            uint64_t g = LDA(goldslot);
            int n2 = 0;
            while ((int)(g >> 32) < 1 && ++n2 < SPIN_MAX) g = LDA(goldslot);
            out[0] = lse - __uint_as_float((uint32_t)g);
        }
    }
}

extern "C" void kernel_launch(void* const* d_in, const int* in_sizes, int n_in,
                              void* d_out, int out_size, void* d_ws, size_t ws_size,
                              hipStream_t stream) {
    const float* feats    = (const float*)d_in[0];
    const float* transfer = (const float*)d_in[1];
    const int*   target   = (const int*)d_in[2];
    float* out = (float*)d_out;
    uint64_t* ws64 = (uint64_t*)d_ws;

    if (ws_size >= (4 * L + 1) * sizeof(uint64_t)) {
        // v7: v4 skeleton + single barrier/step (stale shift) + 2-deep poll
        hipLaunchKernelGGL(crf_v7, dim3(GOLDW + 1), dim3(TPBW), 0, stream,
                           feats, transfer, target, out, ws64);
    } else {
        // proven single-chain fallback (R4): needs only 16392 B of ws
        hipLaunchKernelGGL(crf_single, dim3(NFB + 1), dim3(TPB), 0, stream,
                           feats, transfer, target, out, ws64);
    }
}

// Round 9
// 1669.492 us; speedup vs baseline: 2.3831x; 1.8486x over previous
//
#include <hip/hip_runtime.h>
#include <stdint.h>

#define T_LEN 2048
#define L     1024
#define TPBW  1024          // wide block: 16 waves, 64 columns (4 per wave)
#define NCB   16            // chain blocks per direction
#define COLS  64            // columns (rows) per block
#define GOLDW 32            // gold block id in v4 grid
#define TMID  1023          // forward computes f_{1023}; backward computes b_{1023}
#define BSTEPS 1024         // backward step count (s=1..1024, emission row t=2048-s)
#define SPIN_MAX (1 << 14)  // bounded: wedge exits, normal use 1-3 iters

// legacy fallback geometry
#define NFB   64
#define CPB   16
#define TPB   256

#define SCOPE_AGENT __HIP_MEMORY_SCOPE_AGENT
#define LDA(p) __hip_atomic_load((p), __ATOMIC_RELAXED, SCOPE_AGENT)
#define STA(p, v) __hip_atomic_store((p), (v), __ATOMIC_RELAXED, SCOPE_AGENT)

__device__ __forceinline__ uint64_t pack_su(int tag, float v) {
    return ((uint64_t)(uint32_t)tag << 32) | (uint64_t)__float_as_uint(v);
}

// =====================================================================
// v4 (restored verbatim — measured 1679 us): wide-block meet-in-the-middle,
// agent scope only, no placement assumptions.
//   16 fwd blocks + 16 bwd blocks + 1 gold, 1024 threads each.
//   - per-step handoff = max over 16 writers: minimal skew
//   - each thread polls exactly ONE u64 slot, 1-deep (minimum poll rate;
//     v5/v6/v7 lesson: ANY increase in poll pressure or poll/compute
//     overlap regresses the handoff — fabric contention dominates)
//   - TWO __syncthreads per step: lockstep pacing keeps polls strictly
//     phase-separated from compute+publish (protective, not overhead)
//   - exp-shift is block-local (own previous value via LDS broadcast)
//   - step 1 reads inputs directly: tags written this launch only
// ws layout (u64): fb0[L] fb1[L] bb0[L] bb1[L] gold
// Requires ws >= (4*L + 1) * 8 = 32776 bytes.
// =====================================================================
__global__ __launch_bounds__(TPBW, 1)
void crf_v4(const float* __restrict__ feats,
            const float* __restrict__ transfer,
            const int* __restrict__ target,
            float* __restrict__ out,
            uint64_t* __restrict__ ws64)
{
    __shared__ __align__(16) float qbuf[2][L];      // 8 KB, double-buffered
    __shared__ float red[32];                        // [0..15] max, [16..31] sum
    __shared__ float sh_shift;

    uint64_t* fb0 = ws64;
    uint64_t* fb1 = ws64 + L;
    uint64_t* bb0 = ws64 + 2 * L;
    uint64_t* bb1 = ws64 + 3 * L;
    uint64_t* goldslot = ws64 + 4 * L;

    const int bid  = blockIdx.x;
    const int tid  = threadIdx.x;                    // 0..1023
    const int lane = tid & 63;
    const int wv   = tid >> 6;                       // wave 0..15
    const int cl   = 2 * (lane & 1) + ((lane >> 1) & 1);   // bijective on lanes 0..3

    // ---------------- gold block ----------------
    if (bid == GOLDW) {
        float s = 0.f;
        for (int t = tid; t < T_LEN; t += TPBW)
            s += feats[t * L + target[t]];
        for (int t = tid; t < T_LEN - 1; t += TPBW)
            s += transfer[target[t] * L + target[t + 1]];
        #pragma unroll
        for (int m = 32; m; m >>= 1) s += __shfl_xor(s, m, 64);
        if (lane == 0) red[wv] = s;
        __syncthreads();
        if (tid == 0) {
            float g = 0.f;
            #pragma unroll
            for (int i = 0; i < 16; ++i) g += red[i];
            STA(goldslot, pack_su(1, g));
        }
        return;
    }

    if (bid < NCB) {
        // ================= FORWARD chain (16 blocks, 1023 steps) =================
        const int role    = bid;
        const int colbase = role * COLS;
        const int gcb     = colbase + 4 * wv;        // wave's first global column

        float E[16][4];                              // E[k][c]=exp(transfer[lane+64k][gcb+c])
        #pragma unroll
        for (int k = 0; k < 16; ++k) {
            const float4 r = *(const float4*)(transfer + (size_t)(lane + 64 * k) * L + gcb);
            E[k][0] = __expf(r.x); E[k][1] = __expf(r.y);
            E[k][2] = __expf(r.z); E[k][3] = __expf(r.w);
        }

        for (int t = 1; t <= TMID; ++t) {
            const int par = t & 1;
            const uint64_t* rbuf = par ? fb0 : fb1;  // written at t-1
            uint64_t* wbuf = par ? fb1 : fb0;
            const int expect = t - 1;

            const float fe = feats[(size_t)t * L + gcb + cl];   // overlaps poll

            float val, sloc;
            if (t == 1) {
                val  = feats[tid];                   // f_0 = feats[0][tid], direct
                sloc = feats[colbase];
            } else {
                sloc = sh_shift;                     // own previous value (post-barrier)
                const uint64_t* p = rbuf + tid;      // ONE slot per thread, 1-deep
                uint64_t v;
                int n = 0;
                do { v = LDA(p); } while ((int)(v >> 32) < expect && ++n < SPIN_MAX);
                val = __uint_as_float((uint32_t)v);
            }

            float* qb = qbuf[par];
            qb[tid] = __expf(val - sloc);
            __syncthreads();

            float a0 = 0.f, a1 = 0.f, a2 = 0.f, a3 = 0.f;
            #pragma unroll
            for (int k = 0; k < 16; ++k) {
                const float q = qb[lane + 64 * k];   // conflict-free ds_read_b32
                a0 += q * E[k][0]; a1 += q * E[k][1];
                a2 += q * E[k][2]; a3 += q * E[k][3];
            }

            {   // split-reduction: 4 accs -> 1 per lane (col = cl)
                const bool h1 = lane & 1;
                float s0 = h1 ? a0 : a2;  float r0 = __shfl_xor(s0, 1, 64);
                float s1 = h1 ? a1 : a3;  float r1 = __shfl_xor(s1, 1, 64);
                a0 = (h1 ? a2 : a0) + r0;
                a1 = (h1 ? a3 : a1) + r1;
                const bool h2 = lane & 2;
                float s2 = h2 ? a0 : a1;  float r2 = __shfl_xor(s2, 2, 64);
                a0 = (h2 ? a1 : a0) + r2;
            }
            float s = a0;
            s += __shfl_xor(s, 4, 64);
            s += __shfl_xor(s, 8, 64);
            s += __shfl_xor(s, 16, 64);
            s += __shfl_xor(s, 32, 64);

            const float nv = sloc + __logf(s) + fe;
            if (lane < 4)
                STA(&wbuf[gcb + cl], pack_su(t, nv));
            if (tid == 0) sh_shift = nv;             // col colbase value
            __syncthreads();                         // protects sh_shift
        }

        // ---------- role 0: logZ = lse(f_{1023} + b_{1023}) - gold ----------
        if (role == 0) {
            const uint64_t* fp = fb1 + tid;          // t=1023 odd -> fb1
            const uint64_t* bp = bb0 + tid;          // s=1024 even -> bb0
            uint64_t fv_, bv_;
            int n = 0;
            for (;;) {
                fv_ = LDA(fp); bv_ = LDA(bp);
                bool ready = ((int)(fv_ >> 32) >= TMID) & ((int)(bv_ >> 32) >= BSTEPS);
                if (ready || ++n >= SPIN_MAX) break;
            }
            const float sv = __uint_as_float((uint32_t)fv_) + __uint_as_float((uint32_t)bv_);
            float mx = sv;
            #pragma unroll
            for (int m = 32; m; m >>= 1) mx = fmaxf(mx, __shfl_xor(mx, m, 64));
            if (lane == 0) red[wv] = mx;
            __syncthreads();
            float M = red[0];
            #pragma unroll
            for (int i = 1; i < 16; ++i) M = fmaxf(M, red[i]);
            float sm = __expf(sv - M);
            #pragma unroll
            for (int m = 32; m; m >>= 1) sm += __shfl_xor(sm, m, 64);
            if (lane == 0) red[16 + wv] = sm;
            __syncthreads();
            if (tid == 0) {
                float S = 0.f;
                #pragma unroll
                for (int i = 0; i < 16; ++i) S += red[16 + i];
                const float lse = M + __logf(S);
                uint64_t g = LDA(goldslot);
                int n2 = 0;
                while ((int)(g >> 32) < 1 && ++n2 < SPIN_MAX) g = LDA(goldslot);
                out[0] = lse - __uint_as_float((uint32_t)g);
            }
        }
        return;
    }

    if (bid < 2 * NCB) {
        // ================= BACKWARD chain (16 blocks, 1024 steps) =================
        const int role    = bid - NCB;
        const int rowbase = role * COLS + 4 * wv;    // wave's first global row

        // E[k][r] = exp(transfer[(rowbase+r)*L + lane+64k]) — coalesced staging
        float E[16][4];
        #pragma unroll
        for (int r = 0; r < 4; ++r) {
            const float* rowp = transfer + (size_t)(rowbase + r) * L + lane;
            #pragma unroll
            for (int k = 0; k < 16; ++k)
                E[k][r] = __expf(rowp[64 * k]);
        }

        for (int s = 1; s <= BSTEPS; ++s) {
            const int par = s & 1;
            const uint64_t* rbuf = par ? bb0 : bb1;
            uint64_t* wbuf = par ? bb1 : bb0;
            const int expect = s - 1;
            const int t = T_LEN - s;                 // emission row for this step

            const float fvv = feats[(size_t)t * L + tid];   // overlaps poll

            float bval, sb;
            if (s == 1) {
                bval = 0.f; sb = 0.f;                // b_{2047} = 0
            } else {
                sb = sh_shift;
                const uint64_t* p = rbuf + tid;      // ONE slot per thread, 1-deep
                uint64_t v;
                int n = 0;
                do { v = LDA(p); } while ((int)(v >> 32) < expect && ++n < SPIN_MAX);
                bval = __uint_as_float((uint32_t)v);
            }

            // w_j = exp(feats[t][j] + b[j] - sb) -> LDS broadcast
            float* qb = qbuf[par];
            qb[tid] = __expf(fvv + bval - sb);
            __syncthreads();

            // matvec: acc[r] += w[lane+64k] * E[k][r]
            float a0 = 0.f, a1 = 0.f, a2 = 0.f, a3 = 0.f;
            #pragma unroll
            for (int k = 0; k < 16; ++k) {
                const float w = qb[lane + 64 * k];
                a0 += w * E[k][0]; a1 += w * E[k][1];
                a2 += w * E[k][2]; a3 += w * E[k][3];
            }

            {   // split-reduction: 4 accs -> 1 per lane (row = cl)
                const bool h1 = lane & 1;
                float s0 = h1 ? a0 : a2;  float r0 = __shfl_xor(s0, 1, 64);
                float s1 = h1 ? a1 : a3;  float r1 = __shfl_xor(s1, 1, 64);
                a0 = (h1 ? a2 : a0) + r0;
                a1 = (h1 ? a3 : a1) + r1;
                const bool h2 = lane & 2;
                float s2 = h2 ? a0 : a1;  float r2 = __shfl_xor(s2, 2, 64);
                a0 = (h2 ? a1 : a0) + r2;
            }
            float sum = a0;
            sum += __shfl_xor(sum, 4, 64);
            sum += __shfl_xor(sum, 8, 64);
            sum += __shfl_xor(sum, 16, 64);
            sum += __shfl_xor(sum, 32, 64);

            const float nb = sb + __logf(sum);       // emission already inside w
            if (lane < 4)
                STA(&wbuf[rowbase + cl], pack_su(s, nb));
            if (tid == 0) sh_shift = nb;
            __syncthreads();
        }
        return;
    }
    // bid in (2*NCB, GOLDW): none launched
}

// =====================================================================
// Fallback: proven single-forward-chain kernel (4.16 ms).
// Requires only (2*L + 1) * 8 = 16392 bytes of ws.
// =====================================================================
__global__ __launch_bounds__(TPB, 1)
void crf_single(const float* __restrict__ feats,
                const float* __restrict__ transfer,
                const int* __restrict__ target,
                float* __restrict__ out,
                uint64_t* __restrict__ ws64)
{
    __shared__ __align__(16) float qbuf[2][L];
    __shared__ float red[8];

    uint64_t* buf0 = ws64;
    uint64_t* buf1 = ws64 + L;
    uint64_t* goldslot = ws64 + 2 * L;

    const int b   = blockIdx.x;
    const int tid = threadIdx.x;
    const int lane = tid & 63;
    const int wv   = tid >> 6;
    const int cl   = 2 * (lane & 1) + ((lane >> 1) & 1);

    if (b == NFB) {
        float s = 0.f;
        for (int t = tid; t < T_LEN; t += TPB)
            s += feats[t * L + target[t]];
        for (int t = tid; t < T_LEN - 1; t += TPB)
            s += transfer[target[t] * L + target[t + 1]];
        #pragma unroll
        for (int m = 32; m; m >>= 1) s += __shfl_xor(s, m, 64);
        if (lane == 0) red[wv] = s;
        __syncthreads();
        if (tid == 0) {
            float g = red[0] + red[1] + red[2] + red[3];
            STA(goldslot, pack_su(1, g));
        }
        return;
    }

    const int gcb    = b * CPB + 4 * wv;
    const int shslot = b * CPB;

    float E[16][4];
    #pragma unroll
    for (int k = 0; k < 16; ++k) {
        const float4 r = *(const float4*)(transfer + (size_t)(lane + 64 * k) * L + gcb);
        E[k][0] = __expf(r.x); E[k][1] = __expf(r.y);
        E[k][2] = __expf(r.z); E[k][3] = __expf(r.w);
    }

    if (tid < CPB) {
        int j = b * CPB + tid;
        STA(&buf0[j], pack_su(0, feats[j]));
    }

    for (int t = 1; t < T_LEN; ++t) {
        uint64_t* rbuf = (t & 1) ? buf0 : buf1;
        uint64_t* wbuf = (t & 1) ? buf1 : buf0;
        const int expect = t - 1;
        const float fe = feats[(size_t)t * L + gcb + cl];

        const uint64_t* rp = rbuf + 4 * tid;
        uint64_t v0, v1, v2, v3, vs;
        int n = 0;
        for (;;) {
            v0 = LDA(rp + 0); v1 = LDA(rp + 1);
            v2 = LDA(rp + 2); v3 = LDA(rp + 3);
            vs = LDA(rbuf + shslot);
            bool ready = ((int)(v0 >> 32) >= expect) & ((int)(v1 >> 32) >= expect) &
                         ((int)(v2 >> 32) >= expect) & ((int)(v3 >> 32) >= expect) &
                         ((int)(vs >> 32) >= expect);
            if (ready || ++n >= SPIN_MAX) break;
        }
        const float sloc = __uint_as_float((uint32_t)vs);

        float* qb = qbuf[t & 1];
        float4 qv;
        qv.x = __expf(__uint_as_float((uint32_t)v0) - sloc);
        qv.y = __expf(__uint_as_float((uint32_t)v1) - sloc);
        qv.z = __expf(__uint_as_float((uint32_t)v2) - sloc);
        qv.w = __expf(__uint_as_float((uint32_t)v3) - sloc);
        ((float4*)qb)[tid] = qv;
        __syncthreads();

        float a0 = 0.f, a1 = 0.f, a2 = 0.f, a3 = 0.f;
        #pragma unroll
        for (int k = 0; k < 16; ++k) {
            const float q = qb[lane + 64 * k];
            a0 += q * E[k][0]; a1 += q * E[k][1];
            a2 += q * E[k][2]; a3 += q * E[k][3];
        }
        {
            const bool h1 = lane & 1;
            float s0 = h1 ? a0 : a2;  float r0 = __shfl_xor(s0, 1, 64);
            float s1 = h1 ? a1 : a3;  float r1 = __shfl_xor(s1, 1, 64);
            a0 = (h1 ? a2 : a0) + r0;
            a1 = (h1 ? a3 : a1) + r1;
            const bool h2 = lane & 2;
            float s2 = h2 ? a0 : a1;  float r2 = __shfl_xor(s2, 2, 64);
            a0 = (h2 ? a1 : a0) + r2;
        }
        float s = a0;
        s += __shfl_xor(s, 4, 64);
        s += __shfl_xor(s, 8, 64);
        s += __shfl_xor(s, 16, 64);
        s += __shfl_xor(s, 32, 64);

        const float nv = sloc + __logf(s) + fe;
        if (lane < 4)
            STA(&wbuf[gcb + cl], pack_su(t, nv));
    }

    if (b == 0) {
        const uint64_t* fp = buf1 + 4 * tid;
        uint64_t v0, v1, v2, v3;
        int n = 0;
        for (;;) {
            v0 = LDA(fp + 0); v1 = LDA(fp + 1);
            v2 = LDA(fp + 2); v3 = LDA(fp + 3);
            bool ready = ((int)(v0 >> 32) >= T_LEN - 1) & ((int)(v1 >> 32) >= T_LEN - 1) &
                         ((int)(v2 >> 32) >= T_LEN - 1) & ((int)(v3 >> 32) >= T_LEN - 1);
            if (ready || ++n >= SPIN_MAX) break;
        }
        float sv[4] = { __uint_as_float((uint32_t)v0), __uint_as_float((uint32_t)v1),
                        __uint_as_float((uint32_t)v2), __uint_as_float((uint32_t)v3) };
        float mx = fmaxf(fmaxf(sv[0], sv[1]), fmaxf(sv[2], sv[3]));
        #pragma unroll
        for (int m = 32; m; m >>= 1) mx = fmaxf(mx, __shfl_xor(mx, m, 64));
        if (lane == 0) red[wv] = mx;
        __syncthreads();
        const float M = fmaxf(fmaxf(red[0], red[1]), fmaxf(red[2], red[3]));
        float sm = 0.f;
        #pragma unroll
        for (int k = 0; k < 4; ++k) sm += __expf(sv[k] - M);
        #pragma unroll
        for (int m = 32; m; m >>= 1) sm += __shfl_xor(sm, m, 64);
        if (lane == 0) red[4 + wv] = sm;
        __syncthreads();
        if (tid == 0) {
            const float S = red[4] + red[5] + red[6] + red[7];
            const float lse = M + __logf(S);
            uint64_t g = LDA(goldslot);
            int n2 = 0;
            while ((int)(g >> 32) < 1 && ++n2 < SPIN_MAX) g = LDA(goldslot);
            out[0] = lse - __uint_as_float((uint32_t)g);
        }
    }
}

extern "C" void kernel_launch(void* const* d_in, const int* in_sizes, int n_in,
                              void* d_out, int out_size, void* d_ws, size_t ws_size,
                              hipStream_t stream) {
    const float* feats    = (const float*)d_in[0];
    const float* transfer = (const float*)d_in[1];
    const int*   target   = (const int*)d_in[2];
    float* out = (float*)d_out;
    uint64_t* ws64 = (uint64_t*)d_ws;

    if (ws_size >= (4 * L + 1) * sizeof(uint64_t)) {
        // v4 restored: wide-block MITM, 1-deep own-slot polls, 2 barriers/step
        hipLaunchKernelGGL(crf_v4, dim3(GOLDW + 1), dim3(TPBW), 0, stream,
                           feats, transfer, target, out, ws64);
    } else {
        // proven single-chain fallback (R4): needs only 16392 B of ws
        hipLaunchKernelGGL(crf_single, dim3(NFB + 1), dim3(TPB), 0, stream,
                           feats, transfer, target, out, ws64);
    }
}